// Round 6
// baseline (546.918 us; speedup 1.0000x reference)
//
#include <hip/hip_runtime.h>
#include <cstdint>
#include <cstddef>
#include <math.h>

#define NT 256
#define TROWS 64

__device__ __forceinline__ uint32_t f2u(float f) {
  uint32_t b = __float_as_uint(f);
  return (b & 0x80000000u) ? ~b : (b | 0x80000000u);
}

// Exact k-th largest per row via bitwise binary search in sortable-uint
// space; mask in place: keep raw h where boosted >= kth (u-space compare
// == f32 compare, monotone).
template<int NCOL, int K>
__device__ __forceinline__ void kwinners_inplace(
    float* __restrict__ ht, const float* __restrict__ duty,
    float pct, int wid, int lane)
{
  constexpr int Q = (NCOL + 63) / 64;
  const bool active = (NCOL >= 64) || (lane < NCOL);
  float Bq[Q];
#pragma unroll
  for (int q = 0; q < Q; ++q) {
    const int col = active ? (lane + 64 * q) : 0;
    const float arg = 1.4f * (pct - duty[col]);   // f32 op order as ref
    Bq[q] = (float)exp((double)arg);              // correctly-rounded f32 exp
  }
  for (int i = 0; i < 16; ++i) {
    const int row = wid * 16 + i;
    float h[Q];
    uint32_t u[Q];
#pragma unroll
    for (int q = 0; q < Q; ++q) {
      const int col = active ? (lane + 64 * q) : 0;
      h[q] = ht[col * 68 + row];
      u[q] = active ? f2u(h[q] * Bq[q]) : 0u;
    }
    uint32_t prefix = 0u;
#pragma unroll 4
    for (int bit = 31; bit >= 0; --bit) {
      const uint32_t cand = prefix | (1u << bit);
      int cnt = 0;
#pragma unroll
      for (int q = 0; q < Q; ++q)
        cnt += __popcll(__ballot(u[q] >= cand));
      if (cnt >= K) prefix = cand;
    }
#pragma unroll
    for (int q = 0; q < Q; ++q) {
      const int col = lane + 64 * q;
      if (active) ht[col * 68 + row] = (u[q] >= prefix) ? h[q] : 0.0f;
    }
  }
}

__global__ __launch_bounds__(NT, 2) void sparse_fcnet_kernel(
    const float* __restrict__ x,
    const float* __restrict__ w1, const float* __restrict__ b1,
    const float* __restrict__ w2, const float* __restrict__ b2,
    const float* __restrict__ w3, const float* __restrict__ b3,
    const float* __restrict__ w4, const float* __restrict__ b4,
    const float* __restrict__ w5, const float* __restrict__ b5,
    const float* __restrict__ duty1, const float* __restrict__ duty2,
    const float* __restrict__ duty3, const float* __restrict__ duty4,
    float* __restrict__ out)
{
  // LDS: ht[col][row] (stride 68) reused layer to layer; stg for weight tiles.
  __shared__ float ht[256 * 68];   // 69632 B
  __shared__ float stg[2592];      // 10368 B  (total 80000 B -> 2 blocks/CU)

  const int tid  = threadIdx.x;
  const int lane = tid & 63;
  const int wid  = tid >> 6;
  const int R0   = blockIdx.x * TROWS;

  // ---- Layer 1: h1[64][256] = x[64][784] @ w1.T + b1  (serial f32 FMA)
  {
    const int tr = tid & 7;        // rows tr*8..+7
    const int tc = tid >> 3;       // cols tc*8..+7 (0..31)
    float acc[8][8];
#pragma unroll
    for (int i = 0; i < 8; ++i)
#pragma unroll
      for (int j = 0; j < 8; ++j) acc[i][j] = 0.0f;

    float* x_t = stg;              // [8][68]
    float* w_t = stg + 544;        // [8][256]
    const int xr = tid >> 2;       // 0..63
    const int xk = (tid & 3) * 2;  // 0,2,4,6

    for (int c = 0; c < 98; ++c) {
      const int k0 = c * 8;
      __syncthreads();
      const float2 xv = *(const float2*)&x[(size_t)(R0 + xr) * 784 + k0 + xk];
      x_t[xk * 68 + xr]       = xv.x;
      x_t[(xk + 1) * 68 + xr] = xv.y;
      const float4 wv0 = *(const float4*)&w1[(size_t)tid * 784 + k0];
      const float4 wv1 = *(const float4*)&w1[(size_t)tid * 784 + k0 + 4];
      w_t[0 * 256 + tid] = wv0.x;  w_t[1 * 256 + tid] = wv0.y;
      w_t[2 * 256 + tid] = wv0.z;  w_t[3 * 256 + tid] = wv0.w;
      w_t[4 * 256 + tid] = wv1.x;  w_t[5 * 256 + tid] = wv1.y;
      w_t[6 * 256 + tid] = wv1.z;  w_t[7 * 256 + tid] = wv1.w;
      __syncthreads();
#pragma unroll
      for (int kk = 0; kk < 8; ++kk) {
        float a[8], b[8];
        *(float4*)&a[0] = *(const float4*)&x_t[kk * 68 + tr * 8];
        *(float4*)&a[4] = *(const float4*)&x_t[kk * 68 + tr * 8 + 4];
        *(float4*)&b[0] = *(const float4*)&w_t[kk * 256 + tc * 8];
        *(float4*)&b[4] = *(const float4*)&w_t[kk * 256 + tc * 8 + 4];
#pragma unroll
        for (int i = 0; i < 8; ++i)
#pragma unroll
          for (int j = 0; j < 8; ++j)
            acc[i][j] = fmaf(a[i], b[j], acc[i][j]);
      }
    }
    __syncthreads();
#pragma unroll
    for (int j = 0; j < 8; ++j) {
      const int col = tc * 8 + j;
      const float bv = b1[col];
#pragma unroll
      for (int i = 0; i < 8; ++i)
        ht[col * 68 + tr * 8 + i] = acc[i][j] + bv;
    }
  }
  __syncthreads();
  kwinners_inplace<256, 128>(ht, duty1, 0.5f, wid, lane);
  __syncthreads();

  // ---- Layer 2: h2[64][128] = h1m[64][256] @ w2.T + b2
  {
    const int tr = tid & 7;        // rows tr*8..+7
    const int tc = tid >> 3;       // cols tc*4..+3 (0..31)
    float acc[8][4];
#pragma unroll
    for (int i = 0; i < 8; ++i)
#pragma unroll
      for (int j = 0; j < 4; ++j) acc[i][j] = 0.0f;

    float* w2t = stg + 544;        // [16][128]
    const int sc = tid & 127, sk = tid >> 7;

    for (int c = 0; c < 16; ++c) {
      const int k0 = c * 16;
      __syncthreads();
      const float4 v0 = *(const float4*)&w2[(size_t)sc * 256 + k0 + sk * 8];
      const float4 v1 = *(const float4*)&w2[(size_t)sc * 256 + k0 + sk * 8 + 4];
      w2t[(sk * 8 + 0) * 128 + sc] = v0.x;  w2t[(sk * 8 + 1) * 128 + sc] = v0.y;
      w2t[(sk * 8 + 2) * 128 + sc] = v0.z;  w2t[(sk * 8 + 3) * 128 + sc] = v0.w;
      w2t[(sk * 8 + 4) * 128 + sc] = v1.x;  w2t[(sk * 8 + 5) * 128 + sc] = v1.y;
      w2t[(sk * 8 + 6) * 128 + sc] = v1.z;  w2t[(sk * 8 + 7) * 128 + sc] = v1.w;
      __syncthreads();
#pragma unroll
      for (int kkl = 0; kkl < 16; ++kkl) {
        const int kk = k0 + kkl;
        float a[8], b[4];
        *(float4*)&a[0] = *(const float4*)&ht[kk * 68 + tr * 8];
        *(float4*)&a[4] = *(const float4*)&ht[kk * 68 + tr * 8 + 4];
        *(float4*)&b[0] = *(const float4*)&w2t[kkl * 128 + tc * 4];
#pragma unroll
        for (int i = 0; i < 8; ++i)
#pragma unroll
          for (int j = 0; j < 4; ++j)
            acc[i][j] = fmaf(a[i], b[j], acc[i][j]);
      }
    }
    __syncthreads();
#pragma unroll
    for (int j = 0; j < 4; ++j) {
      const int col = tc * 4 + j;
      const float bv = b2[col];
#pragma unroll
      for (int i = 0; i < 8; ++i)
        ht[col * 68 + tr * 8 + i] = acc[i][j] + bv;
    }
  }
  __syncthreads();
  kwinners_inplace<128, 13>(ht, duty2, 0.1f, wid, lane);
  __syncthreads();

  // ---- Layer 3: h3[64][64] = h2m[64][128] @ w3.T + b3
  {
    float* w3t = ht + 8704;        // [128][64], beyond ht2's live region
    const int sc = tid & 63, sq = tid >> 6;  // sq 0..3
#pragma unroll
    for (int m = 0; m < 32; m += 4) {
      const float4 v = *(const float4*)&w3[(size_t)sc * 128 + sq * 32 + m];
      w3t[(sq * 32 + m + 0) * 64 + sc] = v.x;
      w3t[(sq * 32 + m + 1) * 64 + sc] = v.y;
      w3t[(sq * 32 + m + 2) * 64 + sc] = v.z;
      w3t[(sq * 32 + m + 3) * 64 + sc] = v.w;
    }
    __syncthreads();
    const int tr = tid & 15;       // rows tr*4..+3
    const int tc = tid >> 4;       // cols tc*4..+3 (0..15)
    float acc[4][4];
#pragma unroll
    for (int i = 0; i < 4; ++i)
#pragma unroll
      for (int j = 0; j < 4; ++j) acc[i][j] = 0.0f;
#pragma unroll 8
    for (int kk = 0; kk < 128; ++kk) {
      float a[4], b[4];
      *(float4*)&a[0] = *(const float4*)&ht[kk * 68 + tr * 4];
      *(float4*)&b[0] = *(const float4*)&w3t[kk * 64 + tc * 4];
#pragma unroll
      for (int i = 0; i < 4; ++i)
#pragma unroll
        for (int j = 0; j < 4; ++j)
          acc[i][j] = fmaf(a[i], b[j], acc[i][j]);
    }
    __syncthreads();
#pragma unroll
    for (int j = 0; j < 4; ++j) {
      const int col = tc * 4 + j;
      const float bv = b3[col];
#pragma unroll
      for (int i = 0; i < 4; ++i)
        ht[col * 68 + tr * 4 + i] = acc[i][j] + bv;
    }
  }
  __syncthreads();
  kwinners_inplace<64, 32>(ht, duty3, 0.5f, wid, lane);
  __syncthreads();

  // ---- Layer 4: h4[64][32] = h3m[64][64] @ w4.T + b4
  {
    float* w4t = stg;              // [64][32]
    const int sc = tid & 31, sq = tid >> 5;  // sq 0..7
#pragma unroll
    for (int m = 0; m < 8; m += 4) {
      const float4 v = *(const float4*)&w4[(size_t)sc * 64 + sq * 8 + m];
      w4t[(sq * 8 + m + 0) * 32 + sc] = v.x;
      w4t[(sq * 8 + m + 1) * 32 + sc] = v.y;
      w4t[(sq * 8 + m + 2) * 32 + sc] = v.z;
      w4t[(sq * 8 + m + 3) * 32 + sc] = v.w;
    }
    __syncthreads();
    const int tr = tid & 15;       // rows tr*4..+3
    const int tc = tid >> 4;       // cols tc*2..+1 (0..15)
    float acc[4][2];
#pragma unroll
    for (int i = 0; i < 4; ++i)
#pragma unroll
      for (int j = 0; j < 2; ++j) acc[i][j] = 0.0f;
#pragma unroll 8
    for (int kk = 0; kk < 64; ++kk) {
      float a[4];
      *(float4*)&a[0] = *(const float4*)&ht[kk * 68 + tr * 4];
      const float2 b = *(const float2*)&stg[kk * 32 + tc * 2];
#pragma unroll
      for (int i = 0; i < 4; ++i) {
        acc[i][0] = fmaf(a[i], b.x, acc[i][0]);
        acc[i][1] = fmaf(a[i], b.y, acc[i][1]);
      }
    }
    __syncthreads();
#pragma unroll
    for (int j = 0; j < 2; ++j) {
      const int col = tc * 2 + j;
      const float bv = b4[col];
#pragma unroll
      for (int i = 0; i < 4; ++i)
        ht[col * 68 + tr * 4 + i] = acc[i][j] + bv;
    }
  }
  __syncthreads();
  kwinners_inplace<32, 16>(ht, duty4, 0.5f, wid, lane);
  __syncthreads();

  // ---- Layer 5: out[64][10] = h4m[64][32] @ w5.T + b5
  {
    // BUG FIX (R1-R5): w5 has 320 elements but only 256 threads; the old
    // `if (tid < 320)` left stg[256..319] stale -> cols 8,9 garbage.
    for (int m = tid; m < 320; m += NT) stg[m] = w5[m];
    if (tid < 10) stg[320 + tid] = b5[tid];
    __syncthreads();
    for (int o = tid; o < 640; o += NT) {
      const int row = o / 10, col = o % 10;
      float acc = 0.0f;
#pragma unroll
      for (int kk = 0; kk < 32; ++kk)
        acc = fmaf(ht[kk * 68 + row], stg[col * 32 + kk], acc);
      out[(size_t)(R0 + row) * 10 + col] = acc + stg[320 + col];
    }
  }
}

extern "C" void kernel_launch(void* const* d_in, const int* in_sizes, int n_in,
                              void* d_out, int out_size, void* d_ws, size_t ws_size,
                              hipStream_t stream) {
  const float* x     = (const float*)d_in[0];
  const float* w1    = (const float*)d_in[1];
  const float* b1    = (const float*)d_in[2];
  const float* w2    = (const float*)d_in[3];
  const float* b2    = (const float*)d_in[4];
  const float* w3    = (const float*)d_in[5];
  const float* b3    = (const float*)d_in[6];
  const float* w4    = (const float*)d_in[7];
  const float* b4    = (const float*)d_in[8];
  const float* w5    = (const float*)d_in[9];
  const float* b5    = (const float*)d_in[10];
  const float* duty1 = (const float*)d_in[11];
  const float* duty2 = (const float*)d_in[12];
  const float* duty3 = (const float*)d_in[13];
  const float* duty4 = (const float*)d_in[14];
  float* out = (float*)d_out;

  const int rows = in_sizes[0] / 784;
  const int grid = rows / TROWS;
  hipLaunchKernelGGL(sparse_fcnet_kernel, dim3(grid), dim3(NT), 0, stream,
                     x, w1, b1, w2, b2, w3, b3, w4, b4, w5, b5,
                     duty1, duty2, duty3, duty4, out);
}

// Round 7
// 522.648 us; speedup vs baseline: 1.0464x; 1.0464x over previous
//
#include <hip/hip_runtime.h>
#include <cstdint>
#include <cstddef>
#include <math.h>

#define NT 256
#define TROWS 64

__device__ __forceinline__ uint32_t f2u(float f) {
  uint32_t b = __float_as_uint(f);
  return (b & 0x80000000u) ? ~b : (b | 0x80000000u);
}

// Exact k-th largest per row via bitwise binary search in sortable-uint
// space; mask in place: keep raw h where boosted >= kth.
template<int NCOL, int K>
__device__ __forceinline__ void kwinners_inplace(
    float* __restrict__ ht, const float* __restrict__ duty,
    float pct, int wid, int lane)
{
  constexpr int Q = (NCOL + 63) / 64;
  const bool active = (NCOL >= 64) || (lane < NCOL);
  float Bq[Q];
#pragma unroll
  for (int q = 0; q < Q; ++q) {
    const int col = active ? (lane + 64 * q) : 0;
    const float arg = 1.4f * (pct - duty[col]);
    Bq[q] = (float)exp((double)arg);
  }
  for (int i = 0; i < 16; ++i) {
    const int row = wid * 16 + i;
    float h[Q];
    uint32_t u[Q];
#pragma unroll
    for (int q = 0; q < Q; ++q) {
      const int col = active ? (lane + 64 * q) : 0;
      h[q] = ht[col * 68 + row];
      u[q] = active ? f2u(h[q] * Bq[q]) : 0u;
    }
    uint32_t prefix = 0u;
#pragma unroll 4
    for (int bit = 31; bit >= 0; --bit) {
      const uint32_t cand = prefix | (1u << bit);
      int cnt = 0;
#pragma unroll
      for (int q = 0; q < Q; ++q)
        cnt += __popcll(__ballot(u[q] >= cand));
      if (cnt >= K) prefix = cand;
    }
#pragma unroll
    for (int q = 0; q < Q; ++q) {
      const int col = lane + 64 * q;
      if (active) ht[col * 68 + row] = (u[q] >= prefix) ? h[q] : 0.0f;
    }
  }
}

__global__ __launch_bounds__(NT, 2) void sparse_fcnet_kernel(
    const float* __restrict__ x,
    const float* __restrict__ w1, const float* __restrict__ b1,
    const float* __restrict__ w2, const float* __restrict__ b2,
    const float* __restrict__ w3, const float* __restrict__ b3,
    const float* __restrict__ w4, const float* __restrict__ b4,
    const float* __restrict__ w5, const float* __restrict__ b5,
    const float* __restrict__ duty1, const float* __restrict__ duty2,
    const float* __restrict__ duty3, const float* __restrict__ duty4,
    float* __restrict__ out)
{
  __shared__ float ht[256 * 68];   // 69632 B, h[col][row] between layers
  __shared__ float stg[2592];      // 10368 B  (total 80000 B -> 2 blocks/CU)

  const int tid  = threadIdx.x;
  const int lane = tid & 63;
  const int wid  = tid >> 6;
  const int R0   = blockIdx.x * TROWS;

  // ---- Layer 1: h1[64][256] = x[64][784] @ w1.T + b1
  // Mapping: tr = tid>>5 (wave-uniform-ish row group -> broadcast a-reads),
  // tc = tid&31 (b-reads sweep 1KB contiguous, conflict-free).
  // Staging chunk c+1 prefetched into registers during compute of chunk c.
  {
    const int tr = tid >> 5;       // rows tr*8..+7
    const int tc = tid & 31;       // cols tc*8..+7
    float acc[8][8];
#pragma unroll
    for (int i = 0; i < 8; ++i)
#pragma unroll
      for (int j = 0; j < 8; ++j) acc[i][j] = 0.0f;

    float* x_t = stg;              // [8][68]
    float* w_t = stg + 544;        // [8][256]
    const int xr = tid >> 2;       // 0..63
    const int xk = (tid & 3) * 2;  // 0,2,4,6

    // prefetch chunk 0
    float2 xv = *(const float2*)&x[(size_t)(R0 + xr) * 784 + xk];
    float4 wv0 = *(const float4*)&w1[(size_t)tid * 784 + 0];
    float4 wv1 = *(const float4*)&w1[(size_t)tid * 784 + 4];

    for (int c = 0; c < 98; ++c) {
      __syncthreads();             // readers of staging done
      x_t[xk * 68 + xr]       = xv.x;
      x_t[(xk + 1) * 68 + xr] = xv.y;
      w_t[0 * 256 + tid] = wv0.x;  w_t[1 * 256 + tid] = wv0.y;
      w_t[2 * 256 + tid] = wv0.z;  w_t[3 * 256 + tid] = wv0.w;
      w_t[4 * 256 + tid] = wv1.x;  w_t[5 * 256 + tid] = wv1.y;
      w_t[6 * 256 + tid] = wv1.z;  w_t[7 * 256 + tid] = wv1.w;
      if (c < 97) {                // issue next chunk; lands during compute
        const int k0n = (c + 1) * 8;
        xv  = *(const float2*)&x[(size_t)(R0 + xr) * 784 + k0n + xk];
        wv0 = *(const float4*)&w1[(size_t)tid * 784 + k0n];
        wv1 = *(const float4*)&w1[(size_t)tid * 784 + k0n + 4];
      }
      __syncthreads();             // staging visible
#pragma unroll
      for (int kk = 0; kk < 8; ++kk) {
        float a[8], b[8];
        *(float4*)&a[0] = *(const float4*)&x_t[kk * 68 + tr * 8];
        *(float4*)&a[4] = *(const float4*)&x_t[kk * 68 + tr * 8 + 4];
        *(float4*)&b[0] = *(const float4*)&w_t[kk * 256 + tc * 8];
        *(float4*)&b[4] = *(const float4*)&w_t[kk * 256 + tc * 8 + 4];
#pragma unroll
        for (int i = 0; i < 8; ++i)
#pragma unroll
          for (int j = 0; j < 8; ++j)
            acc[i][j] = fmaf(a[i], b[j], acc[i][j]);
      }
    }
    __syncthreads();
#pragma unroll
    for (int j = 0; j < 8; ++j) {
      const int col = tc * 8 + j;
      const float bv = b1[col];
      float4 lo = {acc[0][j] + bv, acc[1][j] + bv, acc[2][j] + bv, acc[3][j] + bv};
      float4 hi = {acc[4][j] + bv, acc[5][j] + bv, acc[6][j] + bv, acc[7][j] + bv};
      *(float4*)&ht[col * 68 + tr * 8]     = lo;
      *(float4*)&ht[col * 68 + tr * 8 + 4] = hi;
    }
  }
  __syncthreads();
  kwinners_inplace<256, 128>(ht, duty1, 0.5f, wid, lane);
  __syncthreads();

  // ---- Layer 2: h2[64][128] = h1m[64][256] @ w2.T + b2 (BK=16, prefetch)
  {
    const int tr = tid >> 5;       // rows tr*8..+7
    const int tc = tid & 31;       // cols tc*4..+3
    float acc[8][4];
#pragma unroll
    for (int i = 0; i < 8; ++i)
#pragma unroll
      for (int j = 0; j < 4; ++j) acc[i][j] = 0.0f;

    float* w2t = stg;              // [16][128]
    const int sc = tid & 127, sk = tid >> 7;

    float4 v0 = *(const float4*)&w2[(size_t)sc * 256 + sk * 8];
    float4 v1 = *(const float4*)&w2[(size_t)sc * 256 + sk * 8 + 4];

    for (int c = 0; c < 16; ++c) {
      const int k0 = c * 16;
      __syncthreads();
      w2t[(sk * 8 + 0) * 128 + sc] = v0.x;  w2t[(sk * 8 + 1) * 128 + sc] = v0.y;
      w2t[(sk * 8 + 2) * 128 + sc] = v0.z;  w2t[(sk * 8 + 3) * 128 + sc] = v0.w;
      w2t[(sk * 8 + 4) * 128 + sc] = v1.x;  w2t[(sk * 8 + 5) * 128 + sc] = v1.y;
      w2t[(sk * 8 + 6) * 128 + sc] = v1.z;  w2t[(sk * 8 + 7) * 128 + sc] = v1.w;
      if (c < 15) {
        const int k0n = k0 + 16;
        v0 = *(const float4*)&w2[(size_t)sc * 256 + k0n + sk * 8];
        v1 = *(const float4*)&w2[(size_t)sc * 256 + k0n + sk * 8 + 4];
      }
      __syncthreads();
#pragma unroll
      for (int kkl = 0; kkl < 16; ++kkl) {
        const int kk = k0 + kkl;
        float a[8], b[4];
        *(float4*)&a[0] = *(const float4*)&ht[kk * 68 + tr * 8];
        *(float4*)&a[4] = *(const float4*)&ht[kk * 68 + tr * 8 + 4];
        *(float4*)&b[0] = *(const float4*)&w2t[kkl * 128 + tc * 4];
#pragma unroll
        for (int i = 0; i < 8; ++i)
#pragma unroll
          for (int j = 0; j < 4; ++j)
            acc[i][j] = fmaf(a[i], b[j], acc[i][j]);
      }
    }
    __syncthreads();
#pragma unroll
    for (int j = 0; j < 4; ++j) {
      const int col = tc * 4 + j;
      const float bv = b2[col];
      float4 lo = {acc[0][j] + bv, acc[1][j] + bv, acc[2][j] + bv, acc[3][j] + bv};
      float4 hi = {acc[4][j] + bv, acc[5][j] + bv, acc[6][j] + bv, acc[7][j] + bv};
      *(float4*)&ht[col * 68 + tr * 8]     = lo;
      *(float4*)&ht[col * 68 + tr * 8 + 4] = hi;
    }
  }
  __syncthreads();
  kwinners_inplace<128, 13>(ht, duty2, 0.1f, wid, lane);
  __syncthreads();

  // ---- Layer 3: h3[64][64] = h2m[64][128] @ w3.T + b3
  {
    float* w3t = ht + 8704;        // [128][64], beyond live h2m region
    const int sc = tid & 63, sq = tid >> 6;  // sq 0..3
#pragma unroll
    for (int m = 0; m < 32; m += 4) {
      const float4 v = *(const float4*)&w3[(size_t)sc * 128 + sq * 32 + m];
      w3t[(sq * 32 + m + 0) * 64 + sc] = v.x;
      w3t[(sq * 32 + m + 1) * 64 + sc] = v.y;
      w3t[(sq * 32 + m + 2) * 64 + sc] = v.z;
      w3t[(sq * 32 + m + 3) * 64 + sc] = v.w;
    }
    __syncthreads();
    const int tr = tid >> 4;       // rows tr*4..+3  (broadcast-friendly)
    const int tc = tid & 15;       // cols tc*4..+3
    float acc[4][4];
#pragma unroll
    for (int i = 0; i < 4; ++i)
#pragma unroll
      for (int j = 0; j < 4; ++j) acc[i][j] = 0.0f;
#pragma unroll 8
    for (int kk = 0; kk < 128; ++kk) {
      float a[4], b[4];
      *(float4*)&a[0] = *(const float4*)&ht[kk * 68 + tr * 4];
      *(float4*)&b[0] = *(const float4*)&w3t[kk * 64 + tc * 4];
#pragma unroll
      for (int i = 0; i < 4; ++i)
#pragma unroll
        for (int j = 0; j < 4; ++j)
          acc[i][j] = fmaf(a[i], b[j], acc[i][j]);
    }
    __syncthreads();
#pragma unroll
    for (int j = 0; j < 4; ++j) {
      const int col = tc * 4 + j;
      const float bv = b3[col];
      float4 v = {acc[0][j] + bv, acc[1][j] + bv, acc[2][j] + bv, acc[3][j] + bv};
      *(float4*)&ht[col * 68 + tr * 4] = v;
    }
  }
  __syncthreads();
  kwinners_inplace<64, 32>(ht, duty3, 0.5f, wid, lane);
  __syncthreads();

  // ---- Layer 4: h4[64][32] = h3m[64][64] @ w4.T + b4
  {
    float* w4t = stg;              // [64][32]
    const int sc = tid & 31, sq = tid >> 5;  // sq 0..7
#pragma unroll
    for (int m = 0; m < 8; m += 4) {
      const float4 v = *(const float4*)&w4[(size_t)sc * 64 + sq * 8 + m];
      w4t[(sq * 8 + m + 0) * 32 + sc] = v.x;
      w4t[(sq * 8 + m + 1) * 32 + sc] = v.y;
      w4t[(sq * 8 + m + 2) * 32 + sc] = v.z;
      w4t[(sq * 8 + m + 3) * 32 + sc] = v.w;
    }
    __syncthreads();
    const int tr = tid >> 4;       // rows tr*4..+3
    const int tc = tid & 15;       // cols tc*2..+1
    float acc[4][2];
#pragma unroll
    for (int i = 0; i < 4; ++i)
#pragma unroll
      for (int j = 0; j < 2; ++j) acc[i][j] = 0.0f;
#pragma unroll 8
    for (int kk = 0; kk < 64; ++kk) {
      float a[4];
      *(float4*)&a[0] = *(const float4*)&ht[kk * 68 + tr * 4];
      const float2 b = *(const float2*)&stg[kk * 32 + tc * 2];
#pragma unroll
      for (int i = 0; i < 4; ++i) {
        acc[i][0] = fmaf(a[i], b.x, acc[i][0]);
        acc[i][1] = fmaf(a[i], b.y, acc[i][1]);
      }
    }
    __syncthreads();
#pragma unroll
    for (int j = 0; j < 2; ++j) {
      const int col = tc * 2 + j;
      const float bv = b4[col];
      float4 v = {acc[0][j] + bv, acc[1][j] + bv, acc[2][j] + bv, acc[3][j] + bv};
      *(float4*)&ht[col * 68 + tr * 4] = v;
    }
  }
  __syncthreads();
  kwinners_inplace<32, 16>(ht, duty4, 0.5f, wid, lane);
  __syncthreads();

  // ---- Layer 5: out[64][10] = h4m[64][32] @ w5.T + b5
  {
    for (int m = tid; m < 320; m += NT) stg[m] = w5[m];
    if (tid < 10) stg[320 + tid] = b5[tid];
    __syncthreads();
    for (int o = tid; o < 640; o += NT) {
      const int row = o / 10, col = o % 10;
      float acc = 0.0f;
#pragma unroll
      for (int kk = 0; kk < 32; ++kk)
        acc = fmaf(ht[kk * 68 + row], stg[col * 32 + kk], acc);
      out[(size_t)(R0 + row) * 10 + col] = acc + stg[320 + col];
    }
  }
}

extern "C" void kernel_launch(void* const* d_in, const int* in_sizes, int n_in,
                              void* d_out, int out_size, void* d_ws, size_t ws_size,
                              hipStream_t stream) {
  const float* x     = (const float*)d_in[0];
  const float* w1    = (const float*)d_in[1];
  const float* b1    = (const float*)d_in[2];
  const float* w2    = (const float*)d_in[3];
  const float* b2    = (const float*)d_in[4];
  const float* w3    = (const float*)d_in[5];
  const float* b3    = (const float*)d_in[6];
  const float* w4    = (const float*)d_in[7];
  const float* b4    = (const float*)d_in[8];
  const float* w5    = (const float*)d_in[9];
  const float* b5    = (const float*)d_in[10];
  const float* duty1 = (const float*)d_in[11];
  const float* duty2 = (const float*)d_in[12];
  const float* duty3 = (const float*)d_in[13];
  const float* duty4 = (const float*)d_in[14];
  float* out = (float*)d_out;

  const int rows = in_sizes[0] / 784;
  const int grid = rows / TROWS;
  hipLaunchKernelGGL(sparse_fcnet_kernel, dim3(grid), dim3(NT), 0, stream,
                     x, w1, b1, w2, b2, w3, b3, w4, b4, w5, b5,
                     duty1, duty2, duty3, duty4, out);
}

// Round 8
// 515.771 us; speedup vs baseline: 1.0604x; 1.0133x over previous
//
#include <hip/hip_runtime.h>
#include <cstdint>
#include <cstddef>
#include <math.h>

#define NT 256
#define TROWS 64
#define HS 68   // ht column stride (floats); 16B-aligned, 8 bank-groups

__device__ __forceinline__ uint32_t f2u(float f) {
  uint32_t b = __float_as_uint(f);
  return (b & 0x80000000u) ? ~b : (b | 0x80000000u);
}

// Exact k-th largest per row (binary search in sortable-u32 space).
// float4 row-group loads: lane reads rows r0..r0+3 of its column(s) as one
// ds_read_b128 (8 bank-groups x 8 lanes = conflict-free baseline).
template<int NCOL, int K>
__device__ __forceinline__ void kwinners_inplace(
    float* __restrict__ ht, const float* __restrict__ duty,
    float pct, int wid, int lane)
{
  constexpr int Q = (NCOL + 63) / 64;
  const bool active = (NCOL >= 64) || (lane < NCOL);
  float Bq[Q];
#pragma unroll
  for (int q = 0; q < Q; ++q) {
    const int col = active ? (lane + 64 * q) : 0;
    const float arg = 1.4f * (pct - duty[col]);
    Bq[q] = (float)exp((double)arg);
  }
#pragma unroll
  for (int g = 0; g < 4; ++g) {
    const int r0 = wid * 16 + g * 4;
    float h[Q][4];
    uint32_t u[Q][4];
#pragma unroll
    for (int q = 0; q < Q; ++q) {
      const int col = active ? (lane + 64 * q) : 0;
      *(float4*)&h[q][0] = *(const float4*)&ht[col * HS + r0];
#pragma unroll
      for (int m = 0; m < 4; ++m)
        u[q][m] = active ? f2u(h[q][m] * Bq[q]) : 0u;
    }
#pragma unroll
    for (int m = 0; m < 4; ++m) {
      uint32_t prefix = 0u;
#pragma unroll 4
      for (int bit = 31; bit >= 0; --bit) {
        const uint32_t cand = prefix | (1u << bit);
        int cnt = 0;
#pragma unroll
        for (int q = 0; q < Q; ++q)
          cnt += __popcll(__ballot(u[q][m] >= cand));
        if (cnt >= K) prefix = cand;
      }
#pragma unroll
      for (int q = 0; q < Q; ++q)
        h[q][m] = (u[q][m] >= prefix) ? h[q][m] : 0.0f;
    }
#pragma unroll
    for (int q = 0; q < Q; ++q) {
      const int col = lane + 64 * q;
      if (active) *(float4*)&ht[col * HS + r0] = *(const float4*)&h[q][0];
    }
  }
}

__global__ __launch_bounds__(NT, 2) void sparse_fcnet_kernel(
    const float* __restrict__ x,
    const float* __restrict__ w1, const float* __restrict__ b1,
    const float* __restrict__ w2, const float* __restrict__ b2,
    const float* __restrict__ w3, const float* __restrict__ b3,
    const float* __restrict__ w4, const float* __restrict__ b4,
    const float* __restrict__ w5, const float* __restrict__ b5,
    const float* __restrict__ duty1, const float* __restrict__ duty2,
    const float* __restrict__ duty3, const float* __restrict__ duty4,
    float* __restrict__ out)
{
  __shared__ float ht[256 * HS];   // 69632 B, h[col][row] between layers
  __shared__ float stg[2592];      // 10368 B  (total 80000 B -> 2 blocks/CU)

  const int tid  = threadIdx.x;
  const int lane = tid & 63;
  const int wid  = tid >> 6;
  const int R0   = blockIdx.x * TROWS;

  // ---- Layer 1: h1[64][256] = x[64][784] @ w1.T + b1
  // Wave w: rows w*16..+15 (a-reads wave-uniform broadcast).
  // Lane: cols lane*4..+3 (b-read one lane-contiguous ds_read_b128).
  {
    float acc[16][4];
#pragma unroll
    for (int i = 0; i < 16; ++i)
#pragma unroll
      for (int j = 0; j < 4; ++j) acc[i][j] = 0.0f;

    float* x_t = stg;              // [8][68]
    float* w_t = stg + 544;        // [8][256]
    const int xr = tid >> 2;       // 0..63
    const int xk = (tid & 3) * 2;  // 0,2,4,6

    float2 xv = *(const float2*)&x[(size_t)(R0 + xr) * 784 + xk];
    float4 wv0 = *(const float4*)&w1[(size_t)tid * 784 + 0];
    float4 wv1 = *(const float4*)&w1[(size_t)tid * 784 + 4];

    for (int c = 0; c < 98; ++c) {
      __syncthreads();
      x_t[xk * 68 + xr]       = xv.x;
      x_t[(xk + 1) * 68 + xr] = xv.y;
      w_t[0 * 256 + tid] = wv0.x;  w_t[1 * 256 + tid] = wv0.y;
      w_t[2 * 256 + tid] = wv0.z;  w_t[3 * 256 + tid] = wv0.w;
      w_t[4 * 256 + tid] = wv1.x;  w_t[5 * 256 + tid] = wv1.y;
      w_t[6 * 256 + tid] = wv1.z;  w_t[7 * 256 + tid] = wv1.w;
      if (c < 97) {
        const int k0n = (c + 1) * 8;
        xv  = *(const float2*)&x[(size_t)(R0 + xr) * 784 + k0n + xk];
        wv0 = *(const float4*)&w1[(size_t)tid * 784 + k0n];
        wv1 = *(const float4*)&w1[(size_t)tid * 784 + k0n + 4];
      }
      __syncthreads();
#pragma unroll
      for (int kk = 0; kk < 8; ++kk) {
        float a[16], b[4];
        *(float4*)&a[0]  = *(const float4*)&x_t[kk * 68 + wid * 16];
        *(float4*)&a[4]  = *(const float4*)&x_t[kk * 68 + wid * 16 + 4];
        *(float4*)&a[8]  = *(const float4*)&x_t[kk * 68 + wid * 16 + 8];
        *(float4*)&a[12] = *(const float4*)&x_t[kk * 68 + wid * 16 + 12];
        *(float4*)&b[0]  = *(const float4*)&w_t[kk * 256 + lane * 4];
#pragma unroll
        for (int i = 0; i < 16; ++i)
#pragma unroll
          for (int j = 0; j < 4; ++j)
            acc[i][j] = fmaf(a[i], b[j], acc[i][j]);
      }
    }
    __syncthreads();
#pragma unroll
    for (int j = 0; j < 4; ++j) {
      const int col = lane * 4 + j;
      const float bv = b1[col];
#pragma unroll
      for (int g = 0; g < 4; ++g) {
        float4 v = {acc[g*4+0][j] + bv, acc[g*4+1][j] + bv,
                    acc[g*4+2][j] + bv, acc[g*4+3][j] + bv};
        *(float4*)&ht[col * HS + wid * 16 + g * 4] = v;
      }
    }
  }
  __syncthreads();
  kwinners_inplace<256, 128>(ht, duty1, 0.5f, wid, lane);
  __syncthreads();

  // ---- Layer 2: h2[64][128] = h1m[64][256] @ w2.T + b2  (BK=16, prefetch)
  // Wave: rows w*16..+15; lane: cols lane*2..+1 (b-read ds_read_b64).
  {
    float acc[16][2];
#pragma unroll
    for (int i = 0; i < 16; ++i) { acc[i][0] = 0.0f; acc[i][1] = 0.0f; }

    float* w2t = stg;              // [16][128]
    const int sc = tid & 127, sk = tid >> 7;

    float4 v0 = *(const float4*)&w2[(size_t)sc * 256 + sk * 8];
    float4 v1 = *(const float4*)&w2[(size_t)sc * 256 + sk * 8 + 4];

    for (int c = 0; c < 16; ++c) {
      const int k0 = c * 16;
      __syncthreads();
      w2t[(sk * 8 + 0) * 128 + sc] = v0.x;  w2t[(sk * 8 + 1) * 128 + sc] = v0.y;
      w2t[(sk * 8 + 2) * 128 + sc] = v0.z;  w2t[(sk * 8 + 3) * 128 + sc] = v0.w;
      w2t[(sk * 8 + 4) * 128 + sc] = v1.x;  w2t[(sk * 8 + 5) * 128 + sc] = v1.y;
      w2t[(sk * 8 + 6) * 128 + sc] = v1.z;  w2t[(sk * 8 + 7) * 128 + sc] = v1.w;
      if (c < 15) {
        const int k0n = k0 + 16;
        v0 = *(const float4*)&w2[(size_t)sc * 256 + k0n + sk * 8];
        v1 = *(const float4*)&w2[(size_t)sc * 256 + k0n + sk * 8 + 4];
      }
      __syncthreads();
#pragma unroll
      for (int kkl = 0; kkl < 16; ++kkl) {
        const int kk = k0 + kkl;
        float a[16];
        *(float4*)&a[0]  = *(const float4*)&ht[kk * HS + wid * 16];
        *(float4*)&a[4]  = *(const float4*)&ht[kk * HS + wid * 16 + 4];
        *(float4*)&a[8]  = *(const float4*)&ht[kk * HS + wid * 16 + 8];
        *(float4*)&a[12] = *(const float4*)&ht[kk * HS + wid * 16 + 12];
        const float2 b = *(const float2*)&w2t[kkl * 128 + lane * 2];
#pragma unroll
        for (int i = 0; i < 16; ++i) {
          acc[i][0] = fmaf(a[i], b.x, acc[i][0]);
          acc[i][1] = fmaf(a[i], b.y, acc[i][1]);
        }
      }
    }
    __syncthreads();
#pragma unroll
    for (int j = 0; j < 2; ++j) {
      const int col = lane * 2 + j;
      const float bv = b2[col];
#pragma unroll
      for (int g = 0; g < 4; ++g) {
        float4 v = {acc[g*4+0][j] + bv, acc[g*4+1][j] + bv,
                    acc[g*4+2][j] + bv, acc[g*4+3][j] + bv};
        *(float4*)&ht[col * HS + wid * 16 + g * 4] = v;
      }
    }
  }
  __syncthreads();
  kwinners_inplace<128, 13>(ht, duty2, 0.1f, wid, lane);
  __syncthreads();

  // ---- Layer 3: h3[64][64] = h2m[64][128] @ w3.T + b3
  // Wave: rows w*16..+15; lane: col lane (b-read ds_read_b32 contiguous).
  {
    float* w3t = ht + 128 * HS;    // [128][64], beyond live h2m region
    const int sc = tid & 63, sq = tid >> 6;  // sq 0..3
#pragma unroll
    for (int m = 0; m < 32; m += 4) {
      const float4 v = *(const float4*)&w3[(size_t)sc * 128 + sq * 32 + m];
      w3t[(sq * 32 + m + 0) * 64 + sc] = v.x;
      w3t[(sq * 32 + m + 1) * 64 + sc] = v.y;
      w3t[(sq * 32 + m + 2) * 64 + sc] = v.z;
      w3t[(sq * 32 + m + 3) * 64 + sc] = v.w;
    }
    __syncthreads();
    float acc[16];
#pragma unroll
    for (int i = 0; i < 16; ++i) acc[i] = 0.0f;
#pragma unroll 4
    for (int kk = 0; kk < 128; ++kk) {
      float a[16];
      *(float4*)&a[0]  = *(const float4*)&ht[kk * HS + wid * 16];
      *(float4*)&a[4]  = *(const float4*)&ht[kk * HS + wid * 16 + 4];
      *(float4*)&a[8]  = *(const float4*)&ht[kk * HS + wid * 16 + 8];
      *(float4*)&a[12] = *(const float4*)&ht[kk * HS + wid * 16 + 12];
      const float b = w3t[kk * 64 + lane];
#pragma unroll
      for (int i = 0; i < 16; ++i) acc[i] = fmaf(a[i], b, acc[i]);
    }
    __syncthreads();
    {
      const float bv = b3[lane];
#pragma unroll
      for (int g = 0; g < 4; ++g) {
        float4 v = {acc[g*4+0] + bv, acc[g*4+1] + bv,
                    acc[g*4+2] + bv, acc[g*4+3] + bv};
        *(float4*)&ht[lane * HS + wid * 16 + g * 4] = v;
      }
    }
  }
  __syncthreads();
  kwinners_inplace<64, 32>(ht, duty3, 0.5f, wid, lane);
  __syncthreads();

  // ---- Layer 4: h4[64][32] = h3m[64][64] @ w4.T + b4
  // Wave: rows w*16..+15 split by half-wave (rh); lane&31: col.
  {
    float* w4t = stg;              // [64][32]
    const int sc = tid & 31, sq = tid >> 5;  // sq 0..7
#pragma unroll
    for (int m = 0; m < 8; m += 4) {
      const float4 v = *(const float4*)&w4[(size_t)sc * 64 + sq * 8 + m];
      w4t[(sq * 8 + m + 0) * 32 + sc] = v.x;
      w4t[(sq * 8 + m + 1) * 32 + sc] = v.y;
      w4t[(sq * 8 + m + 2) * 32 + sc] = v.z;
      w4t[(sq * 8 + m + 3) * 32 + sc] = v.w;
    }
    __syncthreads();
    const int rh = lane >> 5;      // 0/1: rows wid*16 + rh*8 .. +7
    const int cl = lane & 31;      // col
    float acc[8];
#pragma unroll
    for (int i = 0; i < 8; ++i) acc[i] = 0.0f;
#pragma unroll 4
    for (int kk = 0; kk < 64; ++kk) {
      float a[8];
      *(float4*)&a[0] = *(const float4*)&ht[kk * HS + wid * 16 + rh * 8];
      *(float4*)&a[4] = *(const float4*)&ht[kk * HS + wid * 16 + rh * 8 + 4];
      const float b = w4t[kk * 32 + cl];
#pragma unroll
      for (int i = 0; i < 8; ++i) acc[i] = fmaf(a[i], b, acc[i]);
    }
    __syncthreads();
    {
      const float bv = b4[cl];
#pragma unroll
      for (int g = 0; g < 2; ++g) {
        float4 v = {acc[g*4+0] + bv, acc[g*4+1] + bv,
                    acc[g*4+2] + bv, acc[g*4+3] + bv};
        *(float4*)&ht[cl * HS + wid * 16 + rh * 8 + g * 4] = v;
      }
    }
  }
  __syncthreads();
  kwinners_inplace<32, 16>(ht, duty4, 0.5f, wid, lane);
  __syncthreads();

  // ---- Layer 5: out[64][10] = h4m[64][32] @ w5.T + b5
  {
    for (int m = tid; m < 320; m += NT) stg[m] = w5[m];
    if (tid < 10) stg[320 + tid] = b5[tid];
    __syncthreads();
    for (int o = tid; o < 640; o += NT) {
      const int row = o / 10, col = o % 10;
      float acc = 0.0f;
#pragma unroll
      for (int kk = 0; kk < 32; ++kk)
        acc = fmaf(ht[kk * HS + row], stg[col * 32 + kk], acc);
      out[(size_t)(R0 + row) * 10 + col] = acc + stg[320 + col];
    }
  }
}

extern "C" void kernel_launch(void* const* d_in, const int* in_sizes, int n_in,
                              void* d_out, int out_size, void* d_ws, size_t ws_size,
                              hipStream_t stream) {
  const float* x     = (const float*)d_in[0];
  const float* w1    = (const float*)d_in[1];
  const float* b1    = (const float*)d_in[2];
  const float* w2    = (const float*)d_in[3];
  const float* b2    = (const float*)d_in[4];
  const float* w3    = (const float*)d_in[5];
  const float* b3    = (const float*)d_in[6];
  const float* w4    = (const float*)d_in[7];
  const float* b4    = (const float*)d_in[8];
  const float* w5    = (const float*)d_in[9];
  const float* b5    = (const float*)d_in[10];
  const float* duty1 = (const float*)d_in[11];
  const float* duty2 = (const float*)d_in[12];
  const float* duty3 = (const float*)d_in[13];
  const float* duty4 = (const float*)d_in[14];
  float* out = (float*)d_out;

  const int rows = in_sizes[0] / 784;
  const int grid = rows / TROWS;
  hipLaunchKernelGGL(sparse_fcnet_kernel, dim3(grid), dim3(NT), 0, stream,
                     x, w1, b1, w2, b2, w3, b3, w4, b4, w5, b5,
                     duty1, duty2, duty3, duty4, out);
}

// Round 9
// 491.411 us; speedup vs baseline: 1.1130x; 1.0496x over previous
//
#include <hip/hip_runtime.h>
#include <cstdint>
#include <cstddef>
#include <math.h>

#define NT 512
#define TROWS 64
#define HS 68   // ht column stride (floats)

__device__ __forceinline__ uint32_t f2u(float f) {
  uint32_t b = __float_as_uint(f);
  return (b & 0x80000000u) ? ~b : (b | 0x80000000u);
}

// Exact k-th largest per row (binary search in sortable-u32 space).
// Wave w owns rows w*8..+7 (2 float4 row-groups per column).
template<int NCOL, int K>
__device__ __forceinline__ void kwinners_inplace(
    float* __restrict__ ht, const float* __restrict__ duty,
    float pct, int wid, int lane)
{
  constexpr int Q = (NCOL + 63) / 64;
  const bool active = (NCOL >= 64) || (lane < NCOL);
  float Bq[Q];
#pragma unroll
  for (int q = 0; q < Q; ++q) {
    const int col = active ? (lane + 64 * q) : 0;
    const float arg = 1.4f * (pct - duty[col]);
    Bq[q] = (float)exp((double)arg);
  }
#pragma unroll
  for (int g = 0; g < 2; ++g) {
    const int r0 = wid * 8 + g * 4;
    float h[Q][4];
    uint32_t u[Q][4];
#pragma unroll
    for (int q = 0; q < Q; ++q) {
      const int col = active ? (lane + 64 * q) : 0;
      *(float4*)&h[q][0] = *(const float4*)&ht[col * HS + r0];
#pragma unroll
      for (int m = 0; m < 4; ++m)
        u[q][m] = active ? f2u(h[q][m] * Bq[q]) : 0u;
    }
#pragma unroll
    for (int m = 0; m < 4; ++m) {
      uint32_t prefix = 0u;
#pragma unroll 4
      for (int bit = 31; bit >= 0; --bit) {
        const uint32_t cand = prefix | (1u << bit);
        int cnt = 0;
#pragma unroll
        for (int q = 0; q < Q; ++q)
          cnt += __popcll(__ballot(u[q][m] >= cand));
        if (cnt >= K) prefix = cand;
      }
#pragma unroll
      for (int q = 0; q < Q; ++q)
        h[q][m] = (u[q][m] >= prefix) ? h[q][m] : 0.0f;
    }
#pragma unroll
    for (int q = 0; q < Q; ++q) {
      const int col = lane + 64 * q;
      if (active) *(float4*)&ht[col * HS + r0] = *(const float4*)&h[q][0];
    }
  }
}

__global__ __launch_bounds__(NT, 4) void sparse_fcnet_kernel(
    const float* __restrict__ x,
    const float* __restrict__ w1, const float* __restrict__ b1,
    const float* __restrict__ w2, const float* __restrict__ b2,
    const float* __restrict__ w3, const float* __restrict__ b3,
    const float* __restrict__ w4, const float* __restrict__ b4,
    const float* __restrict__ w5, const float* __restrict__ b5,
    const float* __restrict__ duty1, const float* __restrict__ duty2,
    const float* __restrict__ duty3, const float* __restrict__ duty4,
    float* __restrict__ out)
{
  __shared__ float ht[256 * HS];   // 69632 B, h[col][row] between layers
  __shared__ float stg[2592];      // 10368 B  (total 80000 B -> 2 blocks/CU)

  const int tid  = threadIdx.x;
  const int lane = tid & 63;
  const int wid  = tid >> 6;       // 0..7
  const int R0   = blockIdx.x * TROWS;

  // ---- Layer 1: h1[64][256] = x[64][784] @ w1.T + b1
  // Wave w: rows w*8..+7 (a-reads wave-uniform); lane: cols lane*4..+3.
  {
    float acc[8][4];
#pragma unroll
    for (int i = 0; i < 8; ++i)
#pragma unroll
      for (int j = 0; j < 4; ++j) acc[i][j] = 0.0f;

    float* x_t = stg;              // [8][68]
    float* w_t = stg + 544;        // [8][256]
    const int xr = tid >> 3;       // 0..63
    const int xk = tid & 7;        // 0..7
    const int wc = tid & 255;      // col
    const int wk = (tid >> 8) * 4; // 0 or 4

    float  xv = x[(size_t)(R0 + xr) * 784 + xk];
    float4 wv = *(const float4*)&w1[(size_t)wc * 784 + wk];

    for (int c = 0; c < 98; ++c) {
      __syncthreads();
      x_t[xk * 68 + xr] = xv;
      w_t[(wk + 0) * 256 + wc] = wv.x;
      w_t[(wk + 1) * 256 + wc] = wv.y;
      w_t[(wk + 2) * 256 + wc] = wv.z;
      w_t[(wk + 3) * 256 + wc] = wv.w;
      if (c < 97) {
        const int k0n = (c + 1) * 8;
        xv = x[(size_t)(R0 + xr) * 784 + k0n + xk];
        wv = *(const float4*)&w1[(size_t)wc * 784 + k0n + wk];
      }
      __syncthreads();
#pragma unroll
      for (int kk = 0; kk < 8; ++kk) {
        float a[8], b[4];
        *(float4*)&a[0] = *(const float4*)&x_t[kk * 68 + wid * 8];
        *(float4*)&a[4] = *(const float4*)&x_t[kk * 68 + wid * 8 + 4];
        *(float4*)&b[0] = *(const float4*)&w_t[kk * 256 + lane * 4];
#pragma unroll
        for (int i = 0; i < 8; ++i)
#pragma unroll
          for (int j = 0; j < 4; ++j)
            acc[i][j] = fmaf(a[i], b[j], acc[i][j]);
      }
    }
    __syncthreads();
#pragma unroll
    for (int j = 0; j < 4; ++j) {
      const int col = lane * 4 + j;
      const float bv = b1[col];
#pragma unroll
      for (int g = 0; g < 2; ++g) {
        float4 v = {acc[g*4+0][j] + bv, acc[g*4+1][j] + bv,
                    acc[g*4+2][j] + bv, acc[g*4+3][j] + bv};
        *(float4*)&ht[col * HS + wid * 8 + g * 4] = v;
      }
    }
  }
  __syncthreads();
  kwinners_inplace<256, 128>(ht, duty1, 0.5f, wid, lane);
  __syncthreads();

  // ---- Layer 2: h2[64][128] = h1m[64][256] @ w2.T + b2  (BK=16, prefetch)
  {
    float acc[8][2];
#pragma unroll
    for (int i = 0; i < 8; ++i) { acc[i][0] = 0.0f; acc[i][1] = 0.0f; }

    float* w2t = stg;              // [16][128]
    const int sc = tid & 127;      // col
    const int sk = (tid >> 7) * 4; // 0,4,8,12

    float4 v0 = *(const float4*)&w2[(size_t)sc * 256 + sk];

    for (int c = 0; c < 16; ++c) {
      const int k0 = c * 16;
      __syncthreads();
      w2t[(sk + 0) * 128 + sc] = v0.x;
      w2t[(sk + 1) * 128 + sc] = v0.y;
      w2t[(sk + 2) * 128 + sc] = v0.z;
      w2t[(sk + 3) * 128 + sc] = v0.w;
      if (c < 15)
        v0 = *(const float4*)&w2[(size_t)sc * 256 + k0 + 16 + sk];
      __syncthreads();
#pragma unroll
      for (int kkl = 0; kkl < 16; ++kkl) {
        const int kk = k0 + kkl;
        float a[8];
        *(float4*)&a[0] = *(const float4*)&ht[kk * HS + wid * 8];
        *(float4*)&a[4] = *(const float4*)&ht[kk * HS + wid * 8 + 4];
        const float2 b = *(const float2*)&w2t[kkl * 128 + lane * 2];
#pragma unroll
        for (int i = 0; i < 8; ++i) {
          acc[i][0] = fmaf(a[i], b.x, acc[i][0]);
          acc[i][1] = fmaf(a[i], b.y, acc[i][1]);
        }
      }
    }
    __syncthreads();
#pragma unroll
    for (int j = 0; j < 2; ++j) {
      const int col = lane * 2 + j;
      const float bv = b2[col];
#pragma unroll
      for (int g = 0; g < 2; ++g) {
        float4 v = {acc[g*4+0][j] + bv, acc[g*4+1][j] + bv,
                    acc[g*4+2][j] + bv, acc[g*4+3][j] + bv};
        *(float4*)&ht[col * HS + wid * 8 + g * 4] = v;
      }
    }
  }
  __syncthreads();
  kwinners_inplace<128, 13>(ht, duty2, 0.1f, wid, lane);
  __syncthreads();

  // ---- Layer 3: h3[64][64] = h2m[64][128] @ w3.T + b3
  {
    float* w3t = ht + 128 * HS;    // [128][64], beyond live h2m region
    const int c3 = tid & 63, kb = (tid >> 6) * 16;  // 16 floats/thread
#pragma unroll
    for (int m = 0; m < 16; m += 4) {
      const float4 v = *(const float4*)&w3[(size_t)c3 * 128 + kb + m];
      w3t[(kb + m + 0) * 64 + c3] = v.x;
      w3t[(kb + m + 1) * 64 + c3] = v.y;
      w3t[(kb + m + 2) * 64 + c3] = v.z;
      w3t[(kb + m + 3) * 64 + c3] = v.w;
    }
    __syncthreads();
    float acc[8];
#pragma unroll
    for (int i = 0; i < 8; ++i) acc[i] = 0.0f;
#pragma unroll 4
    for (int kk = 0; kk < 128; ++kk) {
      float a[8];
      *(float4*)&a[0] = *(const float4*)&ht[kk * HS + wid * 8];
      *(float4*)&a[4] = *(const float4*)&ht[kk * HS + wid * 8 + 4];
      const float b = w3t[kk * 64 + lane];
#pragma unroll
      for (int i = 0; i < 8; ++i) acc[i] = fmaf(a[i], b, acc[i]);
    }
    __syncthreads();
    {
      const float bv = b3[lane];
#pragma unroll
      for (int g = 0; g < 2; ++g) {
        float4 v = {acc[g*4+0] + bv, acc[g*4+1] + bv,
                    acc[g*4+2] + bv, acc[g*4+3] + bv};
        *(float4*)&ht[lane * HS + wid * 8 + g * 4] = v;
      }
    }
  }
  __syncthreads();
  kwinners_inplace<64, 32>(ht, duty3, 0.5f, wid, lane);
  __syncthreads();

  // ---- Layer 4: h4[64][32] = h3m[64][64] @ w4.T + b4
  {
    float* w4t = stg;              // [64][32]
    const int c4 = tid & 31, kb = (tid >> 5) * 4;   // 4 floats/thread
    {
      const float4 v = *(const float4*)&w4[(size_t)c4 * 64 + kb];
      w4t[(kb + 0) * 32 + c4] = v.x;
      w4t[(kb + 1) * 32 + c4] = v.y;
      w4t[(kb + 2) * 32 + c4] = v.z;
      w4t[(kb + 3) * 32 + c4] = v.w;
    }
    __syncthreads();
    const int rh = lane >> 5;      // 0/1: rows wid*8 + rh*4 .. +3
    const int cl = lane & 31;      // col
    float acc[4];
#pragma unroll
    for (int i = 0; i < 4; ++i) acc[i] = 0.0f;
#pragma unroll 4
    for (int kk = 0; kk < 64; ++kk) {
      float a[4];
      *(float4*)&a[0] = *(const float4*)&ht[kk * HS + wid * 8 + rh * 4];
      const float b = w4t[kk * 32 + cl];
#pragma unroll
      for (int i = 0; i < 4; ++i) acc[i] = fmaf(a[i], b, acc[i]);
    }
    __syncthreads();
    {
      const float bv = b4[cl];
      float4 v = {acc[0] + bv, acc[1] + bv, acc[2] + bv, acc[3] + bv};
      *(float4*)&ht[cl * HS + wid * 8 + rh * 4] = v;
    }
  }
  __syncthreads();
  kwinners_inplace<32, 16>(ht, duty4, 0.5f, wid, lane);
  __syncthreads();

  // ---- Layer 5: out[64][10] = h4m[64][32] @ w5.T + b5
  {
    if (tid < 320) stg[tid] = w5[tid];
    if (tid < 10)  stg[320 + tid] = b5[tid];
    __syncthreads();
    for (int o = tid; o < 640; o += NT) {
      const int row = o / 10, col = o % 10;
      float acc = 0.0f;
#pragma unroll
      for (int kk = 0; kk < 32; ++kk)
        acc = fmaf(ht[kk * HS + row], stg[col * 32 + kk], acc);
      out[(size_t)(R0 + row) * 10 + col] = acc + stg[320 + col];
    }
  }
}

extern "C" void kernel_launch(void* const* d_in, const int* in_sizes, int n_in,
                              void* d_out, int out_size, void* d_ws, size_t ws_size,
                              hipStream_t stream) {
  const float* x     = (const float*)d_in[0];
  const float* w1    = (const float*)d_in[1];
  const float* b1    = (const float*)d_in[2];
  const float* w2    = (const float*)d_in[3];
  const float* b2    = (const float*)d_in[4];
  const float* w3    = (const float*)d_in[5];
  const float* b3    = (const float*)d_in[6];
  const float* w4    = (const float*)d_in[7];
  const float* b4    = (const float*)d_in[8];
  const float* w5    = (const float*)d_in[9];
  const float* b5    = (const float*)d_in[10];
  const float* duty1 = (const float*)d_in[11];
  const float* duty2 = (const float*)d_in[12];
  const float* duty3 = (const float*)d_in[13];
  const float* duty4 = (const float*)d_in[14];
  float* out = (float*)d_out;

  const int rows = in_sizes[0] / 784;
  const int grid = rows / TROWS;
  hipLaunchKernelGGL(sparse_fcnet_kernel, dim3(grid), dim3(NT), 0, stream,
                     x, w1, b1, w2, b2, w3, b3, w4, b4, w5, b5,
                     duty1, duty2, duty3, duty4, out);
}